// Round 11
// baseline (269.971 us; speedup 1.0000x reference)
//
#include <hip/hip_runtime.h>
#include <math.h>

#define PB 8
#define PL 1024
#define PC 1024
#define PH 16
#define PD 64
#define MAX_SCALE_MUL 4.605170185988092f  // log(100)
#define LOG2E 1.4426950408889634f

typedef __attribute__((ext_vector_type(8))) short s16x8;
typedef __attribute__((ext_vector_type(4))) float f32x4;

#define MFMA16(a, b, c) __builtin_amdgcn_mfma_f32_16x16x32_bf16(a, b, c, 0, 0, 0)

#if __has_builtin(__builtin_amdgcn_exp2f)
#define EXP2(x) __builtin_amdgcn_exp2f(x)
#else
#define EXP2(x) exp2f(x)
#endif

// fp32 -> bf16 round-to-nearest-even (scalar fallback path)
__device__ __forceinline__ unsigned short f2bf(float f) {
    unsigned u = __float_as_uint(f);
    unsigned r = (u + 0x7fffu + ((u >> 16) & 1u)) >> 16;
    return (unsigned short)r;
}

// packed pair fp32x2 -> bf16x2 (low = a, high = b)
__device__ __forceinline__ unsigned pk2bf(float a, float b) {
#if __has_builtin(__builtin_amdgcn_cvt_pk_bf16_f32)
    typedef __attribute__((ext_vector_type(2))) __bf16 bf16x2_t;
    bf16x2_t r = __builtin_amdgcn_cvt_pk_bf16_f32(a, b);
    return __builtin_bit_cast(unsigned, r);
#else
    return (unsigned)f2bf(a) | ((unsigned)f2bf(b) << 16);
#endif
}

// async global->LDS, 16 bytes per lane; lptr must be wave-uniform
__device__ __forceinline__ void gl2lds16(const void* g, void* l) {
    __builtin_amdgcn_global_load_lds(
        (const __attribute__((address_space(1))) unsigned int*)g,
        (__attribute__((address_space(3))) unsigned int*)l, 16, 0, 0);
}

// ---------------------------------------------------------------------------
// cast fp32 -> bf16 for x, W_qkv, W_proj + attn_bias nonzero scan, one launch.
// ---------------------------------------------------------------------------
__global__ __launch_bounds__(256) void cast3f_kernel(
    const float* __restrict__ a, const float* __restrict__ b,
    const float* __restrict__ c, const float* __restrict__ bias,
    unsigned short* __restrict__ oa, unsigned short* __restrict__ ob,
    unsigned short* __restrict__ oc, int* __restrict__ flag)
{
    int blk = blockIdx.x;
    if (blk >= 12288) {
        int idx = (blk - 12288) * 256 + threadIdx.x;
        const float4* b4 = (const float4*)bias;
        bool nz = false;
#pragma unroll
        for (int i = 0; i < 4; i++) {
            float4 v = b4[idx * 4 + i];
            nz |= (v.x != 0.f) | (v.y != 0.f) | (v.z != 0.f) | (v.w != 0.f);
        }
        if (nz) atomicOr(flag, 1);
        return;
    }
    const float* src; unsigned short* dst; int base;
    if (blk < 8192)       { src = a; dst = oa; base = blk; }
    else if (blk < 11264) { src = b; dst = ob; base = blk - 8192; }
    else                  { src = c; dst = oc; base = blk - 11264; }
    int i = base * 256 + threadIdx.x;
    float4 v = ((const float4*)src)[i];
    ((uint2*)dst)[i] = make_uint2(pk2bf(v.x, v.y), pk2bf(v.z, v.w));
}

// ---------------------------------------------------------------------------
// Kernel 1: QKV GEMM (bf16 MFMA), BK=64. R10: + XCD-aware block swizzle (T1):
// nwg%8==0 (1024 / 512), newlin=(lin&7)*(nwg/8)+lin/8 -> each XCD owns
// contiguous n0-rows, so each 256KB Wh panel is fetched once per XCD (L2-hit
// for its 64 m-blocks) instead of ~8x across XCDs.
// ---------------------------------------------------------------------------
template<int VMODE>
__global__ __launch_bounds__(256) void gemm_qkv_lean(
    const unsigned short* __restrict__ Xh,
    const unsigned short* __restrict__ Wh,
    const float* __restrict__ qb, const float* __restrict__ vb,
    const float* __restrict__ freqs,
    unsigned short* __restrict__ Qh, unsigned short* __restrict__ Kh,
    unsigned short* __restrict__ Vt)
{
    __shared__ unsigned short As[128 * 64];
    __shared__ unsigned short Bs[128 * 64];
    const int tid  = threadIdx.x;
    const int wave = tid >> 6, lane = tid & 63;
    const int wm = wave & 1, wn = wave >> 1;
    const int quad = lane >> 4, rr = lane & 15;

    // XCD-aware bijective remap (gridDim.x == 64, nwg % 8 == 0)
    const int nwg    = gridDim.x * gridDim.y;
    const int lin    = blockIdx.y * gridDim.x + blockIdx.x;
    const int newlin = (lin & 7) * (nwg >> 3) + (lin >> 3);
    const int m0 = (newlin & 63) * 128;
    const int n0 = ((newlin >> 6) + (VMODE ? 16 : 0)) * 128;

    f32x4 acc[4][4];   // acc[i][j]: i over W sub-tiles, j over X sub-tiles
#pragma unroll
    for (int i = 0; i < 4; i++)
#pragma unroll
        for (int j = 0; j < 4; j++) acc[i][j] = (f32x4){0.f, 0.f, 0.f, 0.f};

    // staging geometry (BK=64): instr covers 8 rows x 8 chunks of 16B
    const int r8 = lane >> 3;            // row within instr
    const int c8 = lane & 7;             // LDS chunk
    const int g  = c8 ^ r8;              // swizzled global chunk
    const unsigned short* gA = Xh + (size_t)(m0 + wave * 32 + r8) * 1024 + g * 8;
    const unsigned short* gB = Wh + (size_t)(n0 + wave * 32 + r8) * 1024 + g * 8;
    unsigned short* lA = &As[(wave * 32) * 64];
    unsigned short* lB = &Bs[(wave * 32) * 64];

    const int swz8 = rr & 7;

    for (int k0 = 0; k0 < 16; k0++) {
#pragma unroll
        for (int t = 0; t < 4; t++) {
            gl2lds16(gA + (size_t)t * 8192, &lA[(t * 8) * 64]);
            gl2lds16(gB + (size_t)t * 8192, &lB[(t * 8) * 64]);
        }
        gA += 64; gB += 64;
        __syncthreads();

#pragma unroll
        for (int kk = 0; kk < 2; kk++) {
            const int coff = ((kk * 4 + quad) ^ swz8) * 8;
            s16x8 wf[4], xf[4];
#pragma unroll
            for (int i = 0; i < 4; i++)
                wf[i] = *(const s16x8*)&Bs[(wn * 64 + i * 16 + rr) * 64 + coff];
#pragma unroll
            for (int j = 0; j < 4; j++)
                xf[j] = *(const s16x8*)&As[(wm * 64 + j * 16 + rr) * 64 + coff];
            if constexpr (VMODE == 0) {
#pragma unroll
                for (int i = 0; i < 4; i++)
#pragma unroll
                    for (int j = 0; j < 4; j++)
                        acc[i][j] = MFMA16(wf[i], xf[j], acc[i][j]);
            } else {
                // swapped: output row -> X free dim (l), col -> W free dim (d)
#pragma unroll
                for (int i = 0; i < 4; i++)
#pragma unroll
                    for (int j = 0; j < 4; j++)
                        acc[i][j] = MFMA16(xf[j], wf[i], acc[i][j]);
            }
        }
        __syncthreads();
    }

    const int b   = m0 >> 10;
    const int h   = ((n0 & 1023) + wn * 64) >> 6;   // head (uniform per wave)
    const int lb0 = (m0 & 1023) + wm * 64;

    if constexpr (VMODE) {
        // V: acc[i][j] holds l = lb0+j*16+quad*4+reg (contig), d = i*16+rr
        unsigned short* basep = Vt + (size_t)(b * PH + h) * PD * PL;
#pragma unroll
        for (int i = 0; i < 4; i++) {
            const int d = i * 16 + rr;
            const float bv = vb[h * 64 + d];
#pragma unroll
            for (int j = 0; j < 4; j++) {
                const int l0 = lb0 + j * 16 + quad * 4;
                uint2 pk = make_uint2(pk2bf(acc[i][j][0] + bv, acc[i][j][1] + bv),
                                      pk2bf(acc[i][j][2] + bv, acc[i][j][3] + bv));
                *(uint2*)(basep + (size_t)d * PL + l0) = pk;
            }
        }
    } else {
        const int which = n0 >> 10;                 // 0=Q 1=K (uniform)
        if (which == 0) {
            // Q: +bias, raw store; d = i*16+quad*4+reg, l = lb0+j*16+rr
            unsigned short* basep = Qh + (size_t)(b * PH + h) * PL * PD;
#pragma unroll
            for (int i = 0; i < 4; i++) {
                const int d0 = i * 16 + quad * 4;
                const float4 b4 = *(const float4*)(qb + h * 64 + d0);
#pragma unroll
                for (int j = 0; j < 4; j++) {
                    const int l = lb0 + j * 16 + rr;
                    uint2 pk = make_uint2(
                        pk2bf(acc[i][j][0] + b4.x, acc[i][j][1] + b4.y),
                        pk2bf(acc[i][j][2] + b4.z, acc[i][j][3] + b4.w));
                    *(uint2*)(basep + (size_t)l * PD + d0) = pk;
                }
            }
        } else {
            // K: fused l2norm(d) + RoPE on fp32 acc.
            unsigned short* basep = Kh + (size_t)(b * PH + h) * PL * PD;
            const float2* fr2 = (const float2*)freqs;
#pragma unroll
            for (int j = 0; j < 4; j++) {
                float ss = 0.f;
#pragma unroll
                for (int i = 0; i < 4; i++)
                    ss = fmaf(acc[i][j][0], acc[i][j][0],
                         fmaf(acc[i][j][1], acc[i][j][1],
                         fmaf(acc[i][j][2], acc[i][j][2],
                         fmaf(acc[i][j][3], acc[i][j][3], ss))));
                ss += __shfl_xor(ss, 16);   // quad bit0
                ss += __shfl_xor(ss, 32);   // quad bit1
                const float scale = 1.0f / fmaxf(sqrtf(ss), 1e-12f);
                const int l = lb0 + j * 16 + rr;
#pragma unroll
                for (int i = 0; i < 4; i++) {
                    const int d0 = i * 16 + quad * 4;   // even: RoPE pairs reg-adjacent
                    const float2 cs0 = fr2[(size_t)l * 32 + (d0 >> 1)];
                    const float2 cs1 = fr2[(size_t)l * 32 + (d0 >> 1) + 1];
                    const float a0 = acc[i][j][0] * scale, a1 = acc[i][j][1] * scale;
                    const float a2 = acc[i][j][2] * scale, a3 = acc[i][j][3] * scale;
                    uint2 pk = make_uint2(
                        pk2bf(a0 * cs0.x - a1 * cs0.y, fmaf(a0, cs0.y, a1 * cs0.x)),
                        pk2bf(a2 * cs1.x - a3 * cs1.y, fmaf(a2, cs1.y, a3 * cs1.x)));
                    *(uint2*)(basep + (size_t)l * PD + d0) = pk;
                }
            }
        }
    }
}

// ---------------------------------------------------------------------------
// Kernel 3: flash attention — R10 measured: 62.5us, occ 32%, VGPR 64, but
// WRITE_SIZE 23552 (= O 16MB + ~7MB preamble spill under the (256,4) cap).
// This round: (a) preamble recompute-unpack (drop lo[8]/hi[8] arrays; unpack
// uu twice) -> ~16 fewer live regs at the pressure peak -> spill gone;
// (b) XCD swizzle: each XCD owns 16 bh x 8 q-blocks -> its 16 KV sets
// (16x256KB = 4MB) fit its L2 exactly; staging loads become L2-hits.
// ---------------------------------------------------------------------------
__global__ __launch_bounds__(256, 4) void attn_mfma(
    const unsigned short* __restrict__ Qh, const unsigned short* __restrict__ Kh,
    const unsigned short* __restrict__ Vt, const float* __restrict__ bias,
    const float* __restrict__ sml, const int* __restrict__ biasflag,
    const float* __restrict__ freqs, unsigned short* __restrict__ O)
{
    __shared__ unsigned short Ks[2][64 * 64];
    __shared__ unsigned short Vs[2][64 * 64];
    __shared__ unsigned int   Ps[4][16 * 32];   // per-wave P^T pairs, XOR-swizzled

    const int tid  = threadIdx.x;
    const int wave = tid >> 6, lane = tid & 63;
    const int quad = lane >> 4, rr = lane & 15;

    // XCD-aware bijective remap: grid (128 bh, 8 q); lin%8 = XCD round-robin.
    // XCD k gets bh in [16k,16k+16) for all q (KV chunk = 4MB = one L2).
    const int lin = blockIdx.y * 128 + blockIdx.x;
    const int j   = lin >> 3;
    const int bh  = ((lin & 7) << 4) | (j & 15);
    const int q0  = (j >> 4) * 128;

    const int b = bh >> 4, h = bh & 15;
    const int hasbias = *biasflag;

    const float M = __expf(fminf(sml[h], MAX_SCALE_MUL)) * LOG2E;
    const f32x4 negM = (f32x4){-M, -M, -M, -M};

    const int sr = wave * 16 + (lane >> 3);
    const int sc = lane & 7;
    const int sg = sc ^ (sr & 7);               // swizzled global chunk
    const int swz8 = rr & 7;
    const int psw  = (rr & 7) << 2;             // Ps uint-col XOR swizzle

    const size_t kvbase = (size_t)bh * PL * PD; // ELEMENT offset into K/V
    const float2* fr2 = (const float2*)freqs;

    auto stage = [&](int buf, int kb) {
        gl2lds16(Kh + kvbase + (size_t)(kb * 64 + sr) * PD + sg * 8,
                 &Ks[buf][(wave * 16) * 64]);
        gl2lds16(Kh + kvbase + (size_t)(kb * 64 + sr + 8) * PD + sg * 8,
                 &Ks[buf][(wave * 16 + 8) * 64]);
        gl2lds16(Vt + kvbase + (size_t)sr * PL + kb * 64 + sg * 8,
                 &Vs[buf][(wave * 16) * 64]);
        gl2lds16(Vt + kvbase + (size_t)(sr + 8) * PL + kb * 64 + sg * 8,
                 &Vs[buf][(wave * 16 + 8) * 64]);
    };

    // issue first K/V stage now; it completes under the Q preamble below
    stage(0, 0);

    // Q fragments: load raw bf16, norm + scale(M) + RoPE in registers.
    // Recompute-unpack form: only uu[8]+outw[] live (no lo/hi arrays).
    s16x8 qB[2][2];
#pragma unroll
    for (int g = 0; g < 2; g++) {
        const int ql = q0 + g * 64 + wave * 16 + rr;
        const size_t qoff = ((size_t)bh * PL + ql) * PD;
        uint4 r0 = *(const uint4*)(Qh + qoff + quad * 8);
        uint4 r1 = *(const uint4*)(Qh + qoff + 32 + quad * 8);
        unsigned uu[8] = {r0.x, r0.y, r0.z, r0.w, r1.x, r1.y, r1.z, r1.w};
        float ss = 0.f;
#pragma unroll
        for (int m = 0; m < 8; m++) {
            float lo = __uint_as_float(uu[m] << 16);
            float hi = __uint_as_float(uu[m] & 0xffff0000u);
            ss = fmaf(lo, lo, fmaf(hi, hi, ss));
        }
        ss += __shfl_xor(ss, 16);
        ss += __shfl_xor(ss, 32);
        const float scale = M / fmaxf(sqrtf(ss), 1e-12f);
        unsigned outw[8];
#pragma unroll
        for (int m = 0; m < 8; m++) {
            const int idx = (m >> 2) * 16 + quad * 4 + (m & 3);  // freq index
            float2 cs = fr2[(size_t)ql * 32 + idx];
            float lo = __uint_as_float(uu[m] << 16);
            float hi = __uint_as_float(uu[m] & 0xffff0000u);
            float av = lo * scale, bv = hi * scale;
            outw[m] = pk2bf(av * cs.x - bv * cs.y, fmaf(av, cs.y, bv * cs.x));
        }
        qB[g][0] = __builtin_bit_cast(s16x8, make_uint4(outw[0], outw[1], outw[2], outw[3]));
        qB[g][1] = __builtin_bit_cast(s16x8, make_uint4(outw[4], outw[5], outw[6], outw[7]));
    }

    f32x4 accO[2][4];
#pragma unroll
    for (int g = 0; g < 2; g++)
#pragma unroll
        for (int jd = 0; jd < 4; jd++) accO[g][jd] = (f32x4){0.f, 0.f, 0.f, 0.f};
    float lsum[2] = {0.f, 0.f};

    __syncthreads();   // buf 0 ready

    int cur = 0;
    for (int kb = 0; kb < 16; kb++) {
        if (kb < 15) stage(cur ^ 1, kb + 1);   // prefetch: hidden under compute

        // ---- phase 1: S^T - M -> exp2 -> packed bf16, s-outer (kA rolling) ----
        unsigned ps[2][4][2];   // packed P pairs (all indices compile-time)
#pragma unroll
        for (int s = 0; s < 4; s++) {
            const s16x8 k0 = *(const s16x8*)&Ks[cur][(s * 16 + rr) * 64 + ((0 + quad) ^ swz8) * 8];
            const s16x8 k1 = *(const s16x8*)&Ks[cur][(s * 16 + rr) * 64 + ((4 + quad) ^ swz8) * 8];
#pragma unroll
            for (int g = 0; g < 2; g++) {
                __builtin_amdgcn_s_setprio(1);
                f32x4 z = MFMA16(k0, qB[g][0], negM);
                z = MFMA16(k1, qB[g][1], z);
                __builtin_amdgcn_s_setprio(0);
                if (hasbias) {
                    const float* brow = bias + (size_t)(q0 + g * 64 + wave * 16 + rr) * PL + kb * 64;
                    float4 bv = *(const float4*)(brow + s * 16 + quad * 4);
                    z[0] = fmaf(bv.x, LOG2E, z[0]);
                    z[1] = fmaf(bv.y, LOG2E, z[1]);
                    z[2] = fmaf(bv.z, LOG2E, z[2]);
                    z[3] = fmaf(bv.w, LOG2E, z[3]);
                }
                z[0] = EXP2(z[0]); z[1] = EXP2(z[1]);
                z[2] = EXP2(z[2]); z[3] = EXP2(z[3]);
                lsum[g] += (z[0] + z[1]) + (z[2] + z[3]);
                ps[g][s][0] = pk2bf(z[0], z[1]);
                ps[g][s][1] = pk2bf(z[2], z[3]);
            }
        }

        // ---- phase 2: Ps write + pB read for both g, then jd-outer PV ----
        s16x8 pB[2][2];
#pragma unroll
        for (int g = 0; g < 2; g++) {
#pragma unroll
            for (int s = 0; s < 4; s++)
                *(uint2*)&Ps[wave][rr * 32 + ((s * 8 + quad * 2) ^ psw)] =
                    make_uint2(ps[g][s][0], ps[g][s][1]);
            // same-wave LDS ops are in-order: no barrier needed
            pB[g][0] = *(const s16x8*)&Ps[wave][rr * 32 + ((quad * 4) ^ psw)];
            pB[g][1] = *(const s16x8*)&Ps[wave][rr * 32 + ((16 + quad * 4) ^ psw)];
        }
#pragma unroll
        for (int jd = 0; jd < 4; jd++) {
            const s16x8 v0 = *(const s16x8*)&Vs[cur][(jd * 16 + rr) * 64 + ((0 + quad) ^ swz8) * 8];
            const s16x8 v1 = *(const s16x8*)&Vs[cur][(jd * 16 + rr) * 64 + ((4 + quad) ^ swz8) * 8];
            __builtin_amdgcn_s_setprio(1);
#pragma unroll
            for (int g = 0; g < 2; g++) {
                accO[g][jd] = MFMA16(v0, pB[g][0], accO[g][jd]);
                accO[g][jd] = MFMA16(v1, pB[g][1], accO[g][jd]);
            }
            __builtin_amdgcn_s_setprio(0);
        }

        // single barrier per iter: drains the prefetch (full compute phase of
        // latency cover) + releases cur buffer for overwrite next iter
        __syncthreads();
        cur ^= 1;
    }

    // final l reduction across quads; epilogue via per-wave LDS transpose
    const int lr = lane >> 2, cch = lane & 3;
    const int pswl = (lr & 7) << 2;
#pragma unroll
    for (int g = 0; g < 2; g++) {
        float ls = lsum[g];
        ls += __shfl_xor(ls, 16);
        ls += __shfl_xor(ls, 32);
        float inv = 1.0f / ls;
#pragma unroll
        for (int jd = 0; jd < 4; jd++) {
            *(uint2*)&Ps[wave][rr * 32 + ((jd * 8 + quad * 2) ^ psw)] =
                make_uint2(pk2bf(accO[g][jd][0] * inv, accO[g][jd][1] * inv),
                           pk2bf(accO[g][jd][2] * inv, accO[g][jd][3] * inv));
        }
        uint4 w0 = *(const uint4*)&Ps[wave][lr * 32 + ((cch * 8) ^ pswl)];
        uint4 w1 = *(const uint4*)&Ps[wave][lr * 32 + ((cch * 8 + 4) ^ pswl)];
        size_t ob = ((size_t)(b * PL + q0 + g * 64 + wave * 16 + lr) * PC + h * PD);
        *(uint4*)(O + ob + cch * 16)     = w0;
        *(uint4*)(O + ob + cch * 16 + 8) = w1;
    }
}

// ---------------------------------------------------------------------------
// Kernel 4: out-proj GEMM, BK=64. R10: + XCD swizzle (nwg=512, each XCD owns
// one full n0-row -> Wph panel L2-resident for its 64 m-blocks).
// ---------------------------------------------------------------------------
__global__ __launch_bounds__(256) void gemm_proj_mfma(
    const unsigned short* __restrict__ Ah,
    const unsigned short* __restrict__ Wh,
    const float* __restrict__ bp, float* __restrict__ Out)
{
    __shared__ unsigned short As[128 * 64];
    __shared__ unsigned short Bs[128 * 64];
    const int tid  = threadIdx.x;
    const int wave = tid >> 6, lane = tid & 63;
    const int wm = wave & 1, wn = wave >> 1;
    const int quad = lane >> 4, rr = lane & 15;

    const int nwg    = gridDim.x * gridDim.y;
    const int lin    = blockIdx.y * gridDim.x + blockIdx.x;
    const int newlin = (lin & 7) * (nwg >> 3) + (lin >> 3);
    const int m0 = (newlin & 63) * 128;
    const int n0 = (newlin >> 6) * 128;

    f32x4 acc[4][4];   // i over n sub-tiles, j over m sub-tiles
#pragma unroll
    for (int i = 0; i < 4; i++)
#pragma unroll
        for (int j = 0; j < 4; j++) acc[i][j] = (f32x4){0.f, 0.f, 0.f, 0.f};

    const int r8 = lane >> 3;
    const int c8 = lane & 7;
    const int g  = c8 ^ r8;
    const unsigned short* gA = Ah + (size_t)(m0 + wave * 32 + r8) * 1024 + g * 8;
    const unsigned short* gB = Wh + (size_t)(n0 + wave * 32 + r8) * 1024 + g * 8;
    unsigned short* lA = &As[(wave * 32) * 64];
    unsigned short* lB = &Bs[(wave * 32) * 64];

    const int swz8 = rr & 7;

    for (int k0 = 0; k0 < 16; k0++) {
#pragma unroll
        for (int t = 0; t < 4; t++) {
            gl2lds16(gA + (size_t)t * 8192, &lA[(t * 8) * 64]);
            gl2lds16(gB + (size_t)t * 8192, &lB[(t * 8) * 64]);
        }
        gA += 64; gB += 64;
        __syncthreads();

#pragma unroll
        for (int kk = 0; kk < 2; kk++) {
            const int coff = ((kk * 4 + quad) ^ swz8) * 8;
            s16x8 wf[4], xf[4];
#pragma unroll
            for (int i = 0; i < 4; i++)
                wf[i] = *(const s16x8*)&Bs[(wn * 64 + i * 16 + rr) * 64 + coff];
#pragma unroll
            for (int j = 0; j < 4; j++)
                xf[j] = *(const s16x8*)&As[(wm * 64 + j * 16 + rr) * 64 + coff];
#pragma unroll
            for (int i = 0; i < 4; i++)
#pragma unroll
                for (int j = 0; j < 4; j++)
                    acc[i][j] = MFMA16(wf[i], xf[j], acc[i][j]);
        }
        __syncthreads();
    }

    // epilogue: n = n0 + wn*64 + i*16 + quad*4 (+reg), m = m0 + wm*64 + j*16 + rr
#pragma unroll
    for (int i = 0; i < 4; i++) {
        const int nn = n0 + wn * 64 + i * 16 + quad * 4;
        const float4 bb = *(const float4*)(bp + nn);
#pragma unroll
        for (int j = 0; j < 4; j++) {
            const int m = m0 + wm * 64 + j * 16 + rr;
            float4 o = make_float4(acc[i][j][0] + bb.x, acc[i][j][1] + bb.y,
                                   acc[i][j][2] + bb.z, acc[i][j][3] + bb.w);
            *(float4*)(Out + (size_t)m * 1024 + nn) = o;
        }
    }
}

// ---------------------------------------------------------------------------
extern "C" void kernel_launch(void* const* d_in, const int* in_sizes, int n_in,
                              void* d_out, int out_size, void* d_ws, size_t ws_size,
                              hipStream_t stream)
{
    const float* x         = (const float*)d_in[0];
    const float* freqs     = (const float*)d_in[1];
    const float* attn_bias = (const float*)d_in[2];
    const float* W_qkv     = (const float*)d_in[3];
    const float* q_bias    = (const float*)d_in[4];
    const float* v_bias    = (const float*)d_in[5];
    const float* sml       = (const float*)d_in[6];
    const float* W_proj    = (const float*)d_in[7];
    const float* b_proj    = (const float*)d_in[8];
    float* out = (float*)d_out;

    unsigned char* w = (unsigned char*)d_ws;
    const size_t MB = 1ull << 20;
    unsigned short* xh  = (unsigned short*)(w + 0);        // 16 MiB
    unsigned short* wqh = (unsigned short*)(w + 16 * MB);  //  6 MiB
    unsigned short* wph = (unsigned short*)(w + 22 * MB);  //  2 MiB
    unsigned short* Qh  = (unsigned short*)(w + 24 * MB);  // 16 MiB (raw Q+bias)
    unsigned short* Kh  = (unsigned short*)(w + 40 * MB);  // 16 MiB (normed+roped)
    unsigned short* Vt  = (unsigned short*)(w + 72 * MB);  // 16 MiB (B,H,D,L), direct
    unsigned short* Oh  = (unsigned short*)(w + 88 * MB);  // 16 MiB (B,L,H,D)
    int*            flg = (int*)(w + 104 * MB);            //  4 B bias flag

    // 0. zero bias flag (ws is poisoned 0xAA)
    hipMemsetAsync(flg, 0, sizeof(int), stream);
    // 1. fused casts + bias scan
    cast3f_kernel<<<12544, 256, 0, stream>>>(x, W_qkv, W_proj, attn_bias,
                                             xh, wqh, wph, flg);
    // 2a. QKV projection, Q/K halves (K norm+RoPE fused into epilogue)
    gemm_qkv_lean<0><<<dim3(64, 16), 256, 0, stream>>>(
        xh, wqh, q_bias, v_bias, freqs, Qh, Kh, Vt);
    // 2b. QKV projection, V half (swapped MFMA -> direct V^T store)
    gemm_qkv_lean<1><<<dim3(64, 8), 256, 0, stream>>>(
        xh, wqh, q_bias, v_bias, freqs, Qh, Kh, Vt);
    // 3. flash attention (staged dbuf, 4-wave, XCD-swizzled, slim preamble)
    attn_mfma<<<dim3(128, 8), 256, 0, stream>>>(Qh, Kh, Vt, attn_bias, sml, flg, freqs, Oh);
    // 4. output projection (BK=64, XCD-swizzled)
    gemm_proj_mfma<<<dim3(64, 8), 256, 0, stream>>>(Oh, wph, b_proj, out);
}

// Round 12
// 250.886 us; speedup vs baseline: 1.0761x; 1.0761x over previous
//
#include <hip/hip_runtime.h>
#include <math.h>
#include <type_traits>

#define PB 8
#define PL 1024
#define PC 1024
#define PH 16
#define PD 64
#define MAX_SCALE_MUL 4.605170185988092f  // log(100)
#define LOG2E 1.4426950408889634f

typedef __attribute__((ext_vector_type(8))) short s16x8;
typedef __attribute__((ext_vector_type(4))) float f32x4;

#define MFMA16(a, b, c) __builtin_amdgcn_mfma_f32_16x16x32_bf16(a, b, c, 0, 0, 0)

#if __has_builtin(__builtin_amdgcn_exp2f)
#define EXP2(x) __builtin_amdgcn_exp2f(x)
#else
#define EXP2(x) exp2f(x)
#endif

// fp32 -> bf16 round-to-nearest-even (scalar fallback path)
__device__ __forceinline__ unsigned short f2bf(float f) {
    unsigned u = __float_as_uint(f);
    unsigned r = (u + 0x7fffu + ((u >> 16) & 1u)) >> 16;
    return (unsigned short)r;
}

// packed pair fp32x2 -> bf16x2 (low = a, high = b)
__device__ __forceinline__ unsigned pk2bf(float a, float b) {
#if __has_builtin(__builtin_amdgcn_cvt_pk_bf16_f32)
    typedef __attribute__((ext_vector_type(2))) __bf16 bf16x2_t;
    bf16x2_t r = __builtin_amdgcn_cvt_pk_bf16_f32(a, b);
    return __builtin_bit_cast(unsigned, r);
#else
    return (unsigned)f2bf(a) | ((unsigned)f2bf(b) << 16);
#endif
}

// async global->LDS, 16 bytes per lane; lptr must be wave-uniform
__device__ __forceinline__ void gl2lds16(const void* g, void* l) {
    __builtin_amdgcn_global_load_lds(
        (const __attribute__((address_space(1))) unsigned int*)g,
        (__attribute__((address_space(3))) unsigned int*)l, 16, 0, 0);
}

// ---------------------------------------------------------------------------
// cast fp32 -> bf16 for x, W_qkv, W_proj + attn_bias nonzero scan, one launch.
// ---------------------------------------------------------------------------
__global__ __launch_bounds__(256) void cast3f_kernel(
    const float* __restrict__ a, const float* __restrict__ b,
    const float* __restrict__ c, const float* __restrict__ bias,
    unsigned short* __restrict__ oa, unsigned short* __restrict__ ob,
    unsigned short* __restrict__ oc, int* __restrict__ flag)
{
    int blk = blockIdx.x;
    if (blk >= 12288) {
        int idx = (blk - 12288) * 256 + threadIdx.x;
        const float4* b4 = (const float4*)bias;
        bool nz = false;
#pragma unroll
        for (int i = 0; i < 4; i++) {
            float4 v = b4[idx * 4 + i];
            nz |= (v.x != 0.f) | (v.y != 0.f) | (v.z != 0.f) | (v.w != 0.f);
        }
        if (nz) atomicOr(flag, 1);
        return;
    }
    const float* src; unsigned short* dst; int base;
    if (blk < 8192)       { src = a; dst = oa; base = blk; }
    else if (blk < 11264) { src = b; dst = ob; base = blk - 8192; }
    else                  { src = c; dst = oc; base = blk - 11264; }
    int i = base * 256 + threadIdx.x;
    float4 v = ((const float4*)src)[i];
    ((uint2*)dst)[i] = make_uint2(pk2bf(v.x, v.y), pk2bf(v.z, v.w));
}

// ---------------------------------------------------------------------------
// Kernel 1: QKV GEMM (bf16 MFMA), BK=64. R12: single launch for all 3072
// output cols (grid 64 x 24; vmode = n0>=2048 selects the swapped-MFMA V
// path). NO XCD swizzle (R11 lesson: default mapping already co-locates all
// n-blocks of an m0 on one XCD -> X panels L2-resident; swizzling for W
// re-fetched X 8x and regressed). K-loops duplicated per vmode for clean
// scheduling (uniform branch hoisted out of the hot loop).
// ---------------------------------------------------------------------------
__global__ __launch_bounds__(256) void gemm_qkv_lean(
    const unsigned short* __restrict__ Xh,
    const unsigned short* __restrict__ Wh,
    const float* __restrict__ qb, const float* __restrict__ vb,
    const float* __restrict__ freqs,
    unsigned short* __restrict__ Qh, unsigned short* __restrict__ Kh,
    unsigned short* __restrict__ Vt)
{
    __shared__ unsigned short As[128 * 64];
    __shared__ unsigned short Bs[128 * 64];
    const int tid  = threadIdx.x;
    const int wave = tid >> 6, lane = tid & 63;
    const int wm = wave & 1, wn = wave >> 1;
    const int quad = lane >> 4, rr = lane & 15;
    const int m0 = blockIdx.x * 128;
    const int n0 = blockIdx.y * 128;          // [0,3072): 0-2047 QK, 2048+ V
    const bool vmode = (n0 >= 2048);

    f32x4 acc[4][4];   // acc[i][j]: i over W sub-tiles, j over X sub-tiles
#pragma unroll
    for (int i = 0; i < 4; i++)
#pragma unroll
        for (int j = 0; j < 4; j++) acc[i][j] = (f32x4){0.f, 0.f, 0.f, 0.f};

    // staging geometry (BK=64): instr covers 8 rows x 8 chunks of 16B
    const int r8 = lane >> 3;            // row within instr
    const int c8 = lane & 7;             // LDS chunk
    const int g  = c8 ^ r8;              // swizzled global chunk
    const unsigned short* gA = Xh + (size_t)(m0 + wave * 32 + r8) * 1024 + g * 8;
    const unsigned short* gB = Wh + (size_t)(n0 + wave * 32 + r8) * 1024 + g * 8;
    unsigned short* lA = &As[(wave * 32) * 64];
    unsigned short* lB = &Bs[(wave * 32) * 64];

    const int swz8 = rr & 7;

    auto kloop = [&](auto vm) {
        constexpr int VM = decltype(vm)::value;
        for (int k0 = 0; k0 < 16; k0++) {
#pragma unroll
            for (int t = 0; t < 4; t++) {
                gl2lds16(gA + (size_t)t * 8192, &lA[(t * 8) * 64]);
                gl2lds16(gB + (size_t)t * 8192, &lB[(t * 8) * 64]);
            }
            gA += 64; gB += 64;
            __syncthreads();

#pragma unroll
            for (int kk = 0; kk < 2; kk++) {
                const int coff = ((kk * 4 + quad) ^ swz8) * 8;
                s16x8 wf[4], xf[4];
#pragma unroll
                for (int i = 0; i < 4; i++)
                    wf[i] = *(const s16x8*)&Bs[(wn * 64 + i * 16 + rr) * 64 + coff];
#pragma unroll
                for (int j = 0; j < 4; j++)
                    xf[j] = *(const s16x8*)&As[(wm * 64 + j * 16 + rr) * 64 + coff];
                if constexpr (VM == 0) {
#pragma unroll
                    for (int i = 0; i < 4; i++)
#pragma unroll
                        for (int j = 0; j < 4; j++)
                            acc[i][j] = MFMA16(wf[i], xf[j], acc[i][j]);
                } else {
                    // swapped: output row -> X free dim (l), col -> W free dim (d)
#pragma unroll
                    for (int i = 0; i < 4; i++)
#pragma unroll
                        for (int j = 0; j < 4; j++)
                            acc[i][j] = MFMA16(xf[j], wf[i], acc[i][j]);
                }
            }
            __syncthreads();
        }
    };
    if (vmode) kloop(std::integral_constant<int, 1>{});
    else       kloop(std::integral_constant<int, 0>{});

    const int b   = m0 >> 10;
    const int h   = ((n0 & 1023) + wn * 64) >> 6;   // head (uniform per wave)
    const int lb0 = (m0 & 1023) + wm * 64;

    if (vmode) {
        // V: acc[i][j] holds l = lb0+j*16+quad*4+reg (contig), d = i*16+rr
        unsigned short* basep = Vt + (size_t)(b * PH + h) * PD * PL;
#pragma unroll
        for (int i = 0; i < 4; i++) {
            const int d = i * 16 + rr;
            const float bv = vb[h * 64 + d];
#pragma unroll
            for (int j = 0; j < 4; j++) {
                const int l0 = lb0 + j * 16 + quad * 4;
                uint2 pk = make_uint2(pk2bf(acc[i][j][0] + bv, acc[i][j][1] + bv),
                                      pk2bf(acc[i][j][2] + bv, acc[i][j][3] + bv));
                *(uint2*)(basep + (size_t)d * PL + l0) = pk;
            }
        }
    } else {
        const int which = n0 >> 10;                 // 0=Q 1=K (uniform)
        if (which == 0) {
            // Q: +bias, raw store; d = i*16+quad*4+reg, l = lb0+j*16+rr
            unsigned short* basep = Qh + (size_t)(b * PH + h) * PL * PD;
#pragma unroll
            for (int i = 0; i < 4; i++) {
                const int d0 = i * 16 + quad * 4;
                const float4 b4 = *(const float4*)(qb + h * 64 + d0);
#pragma unroll
                for (int j = 0; j < 4; j++) {
                    const int l = lb0 + j * 16 + rr;
                    uint2 pk = make_uint2(
                        pk2bf(acc[i][j][0] + b4.x, acc[i][j][1] + b4.y),
                        pk2bf(acc[i][j][2] + b4.z, acc[i][j][3] + b4.w));
                    *(uint2*)(basep + (size_t)l * PD + d0) = pk;
                }
            }
        } else {
            // K: fused l2norm(d) + RoPE on fp32 acc.
            unsigned short* basep = Kh + (size_t)(b * PH + h) * PL * PD;
            const float2* fr2 = (const float2*)freqs;
#pragma unroll
            for (int j = 0; j < 4; j++) {
                float ss = 0.f;
#pragma unroll
                for (int i = 0; i < 4; i++)
                    ss = fmaf(acc[i][j][0], acc[i][j][0],
                         fmaf(acc[i][j][1], acc[i][j][1],
                         fmaf(acc[i][j][2], acc[i][j][2],
                         fmaf(acc[i][j][3], acc[i][j][3], ss))));
                ss += __shfl_xor(ss, 16);   // quad bit0
                ss += __shfl_xor(ss, 32);   // quad bit1
                const float scale = 1.0f / fmaxf(sqrtf(ss), 1e-12f);
                const int l = lb0 + j * 16 + rr;
#pragma unroll
                for (int i = 0; i < 4; i++) {
                    const int d0 = i * 16 + quad * 4;   // even: RoPE pairs reg-adjacent
                    const float2 cs0 = fr2[(size_t)l * 32 + (d0 >> 1)];
                    const float2 cs1 = fr2[(size_t)l * 32 + (d0 >> 1) + 1];
                    const float a0 = acc[i][j][0] * scale, a1 = acc[i][j][1] * scale;
                    const float a2 = acc[i][j][2] * scale, a3 = acc[i][j][3] * scale;
                    uint2 pk = make_uint2(
                        pk2bf(a0 * cs0.x - a1 * cs0.y, fmaf(a0, cs0.y, a1 * cs0.x)),
                        pk2bf(a2 * cs1.x - a3 * cs1.y, fmaf(a2, cs1.y, a3 * cs1.x)));
                    *(uint2*)(basep + (size_t)l * PD + d0) = pk;
                }
            }
        }
    }
}

// ---------------------------------------------------------------------------
// Kernel 3: flash attention — R10 structure (best: 62.5us, occ 32, VGPR 64)
// with the kb-loop DUPLICATED on the uniform hasbias branch. R10/R11 showed
// WRITE_SIZE 23552 (7MB spill) that recompute-unpack didn't fix -> the
// spill is the BIAS path's extra live values inflating worst-case pressure
// under the 128-reg cap. Splitting the loop per path puts spill code only
// on the (runtime-dead) bias copy; the nobias copy (~94 live regs) runs
// spill-free. NO XCD swizzle (R11: neutral-negative).
// ---------------------------------------------------------------------------
__global__ __launch_bounds__(256, 4) void attn_mfma(
    const unsigned short* __restrict__ Qh, const unsigned short* __restrict__ Kh,
    const unsigned short* __restrict__ Vt, const float* __restrict__ bias,
    const float* __restrict__ sml, const int* __restrict__ biasflag,
    const float* __restrict__ freqs, unsigned short* __restrict__ O)
{
    __shared__ unsigned short Ks[2][64 * 64];
    __shared__ unsigned short Vs[2][64 * 64];
    __shared__ unsigned int   Ps[4][16 * 32];   // per-wave P^T pairs, XOR-swizzled

    const int tid  = threadIdx.x;
    const int wave = tid >> 6, lane = tid & 63;
    const int quad = lane >> 4, rr = lane & 15;
    const int bh = blockIdx.x, q0 = blockIdx.y * 128;
    const int b = bh >> 4, h = bh & 15;
    const int hasbias = *biasflag;

    const float M = __expf(fminf(sml[h], MAX_SCALE_MUL)) * LOG2E;
    const f32x4 negM = (f32x4){-M, -M, -M, -M};

    const int sr = wave * 16 + (lane >> 3);
    const int sc = lane & 7;
    const int sg = sc ^ (sr & 7);               // swizzled global chunk
    const int swz8 = rr & 7;
    const int psw  = (rr & 7) << 2;             // Ps uint-col XOR swizzle

    const size_t kvbase = (size_t)bh * PL * PD; // ELEMENT offset into K/V
    const float2* fr2 = (const float2*)freqs;

    auto stage = [&](int buf, int kb) {
        gl2lds16(Kh + kvbase + (size_t)(kb * 64 + sr) * PD + sg * 8,
                 &Ks[buf][(wave * 16) * 64]);
        gl2lds16(Kh + kvbase + (size_t)(kb * 64 + sr + 8) * PD + sg * 8,
                 &Ks[buf][(wave * 16 + 8) * 64]);
        gl2lds16(Vt + kvbase + (size_t)sr * PL + kb * 64 + sg * 8,
                 &Vs[buf][(wave * 16) * 64]);
        gl2lds16(Vt + kvbase + (size_t)(sr + 8) * PL + kb * 64 + sg * 8,
                 &Vs[buf][(wave * 16 + 8) * 64]);
    };

    // issue first K/V stage now; it completes under the Q preamble below
    stage(0, 0);

    // Q fragments: load raw bf16, norm + scale(M) + RoPE in registers.
    // Recompute-unpack form: only uu[8]+outw[] live (no lo/hi arrays).
    s16x8 qB[2][2];
#pragma unroll
    for (int g = 0; g < 2; g++) {
        const int ql = q0 + g * 64 + wave * 16 + rr;
        const size_t qoff = ((size_t)bh * PL + ql) * PD;
        uint4 r0 = *(const uint4*)(Qh + qoff + quad * 8);
        uint4 r1 = *(const uint4*)(Qh + qoff + 32 + quad * 8);
        unsigned uu[8] = {r0.x, r0.y, r0.z, r0.w, r1.x, r1.y, r1.z, r1.w};
        float ss = 0.f;
#pragma unroll
        for (int m = 0; m < 8; m++) {
            float lo = __uint_as_float(uu[m] << 16);
            float hi = __uint_as_float(uu[m] & 0xffff0000u);
            ss = fmaf(lo, lo, fmaf(hi, hi, ss));
        }
        ss += __shfl_xor(ss, 16);
        ss += __shfl_xor(ss, 32);
        const float scale = M / fmaxf(sqrtf(ss), 1e-12f);
        unsigned outw[8];
#pragma unroll
        for (int m = 0; m < 8; m++) {
            const int idx = (m >> 2) * 16 + quad * 4 + (m & 3);  // freq index
            float2 cs = fr2[(size_t)ql * 32 + idx];
            float lo = __uint_as_float(uu[m] << 16);
            float hi = __uint_as_float(uu[m] & 0xffff0000u);
            float av = lo * scale, bv = hi * scale;
            outw[m] = pk2bf(av * cs.x - bv * cs.y, fmaf(av, cs.y, bv * cs.x));
        }
        qB[g][0] = __builtin_bit_cast(s16x8, make_uint4(outw[0], outw[1], outw[2], outw[3]));
        qB[g][1] = __builtin_bit_cast(s16x8, make_uint4(outw[4], outw[5], outw[6], outw[7]));
    }

    f32x4 accO[2][4];
#pragma unroll
    for (int g = 0; g < 2; g++)
#pragma unroll
        for (int jd = 0; jd < 4; jd++) accO[g][jd] = (f32x4){0.f, 0.f, 0.f, 0.f};
    float lsum[2] = {0.f, 0.f};

    __syncthreads();   // buf 0 ready

    auto kbloop = [&](auto hb) {
        constexpr int HB = decltype(hb)::value;
        int cur = 0;
        for (int kb = 0; kb < 16; kb++) {
            if (kb < 15) stage(cur ^ 1, kb + 1);   // prefetch under compute

            // ---- phase 1: S^T - M -> exp2 -> packed bf16, s-outer ----
            unsigned ps[2][4][2];   // packed P pairs (compile-time indexed)
#pragma unroll
            for (int s = 0; s < 4; s++) {
                const s16x8 k0 = *(const s16x8*)&Ks[cur][(s * 16 + rr) * 64 + ((0 + quad) ^ swz8) * 8];
                const s16x8 k1 = *(const s16x8*)&Ks[cur][(s * 16 + rr) * 64 + ((4 + quad) ^ swz8) * 8];
#pragma unroll
                for (int g = 0; g < 2; g++) {
                    __builtin_amdgcn_s_setprio(1);
                    f32x4 z = MFMA16(k0, qB[g][0], negM);
                    z = MFMA16(k1, qB[g][1], z);
                    __builtin_amdgcn_s_setprio(0);
                    if constexpr (HB) {
                        const float* brow = bias + (size_t)(q0 + g * 64 + wave * 16 + rr) * PL + kb * 64;
                        float4 bv = *(const float4*)(brow + s * 16 + quad * 4);
                        z[0] = fmaf(bv.x, LOG2E, z[0]);
                        z[1] = fmaf(bv.y, LOG2E, z[1]);
                        z[2] = fmaf(bv.z, LOG2E, z[2]);
                        z[3] = fmaf(bv.w, LOG2E, z[3]);
                    }
                    z[0] = EXP2(z[0]); z[1] = EXP2(z[1]);
                    z[2] = EXP2(z[2]); z[3] = EXP2(z[3]);
                    lsum[g] += (z[0] + z[1]) + (z[2] + z[3]);
                    ps[g][s][0] = pk2bf(z[0], z[1]);
                    ps[g][s][1] = pk2bf(z[2], z[3]);
                }
            }

            // ---- phase 2: Ps write + pB read for both g, then jd-outer PV ----
            s16x8 pB[2][2];
#pragma unroll
            for (int g = 0; g < 2; g++) {
#pragma unroll
                for (int s = 0; s < 4; s++)
                    *(uint2*)&Ps[wave][rr * 32 + ((s * 8 + quad * 2) ^ psw)] =
                        make_uint2(ps[g][s][0], ps[g][s][1]);
                // same-wave LDS ops are in-order: no barrier needed
                pB[g][0] = *(const s16x8*)&Ps[wave][rr * 32 + ((quad * 4) ^ psw)];
                pB[g][1] = *(const s16x8*)&Ps[wave][rr * 32 + ((16 + quad * 4) ^ psw)];
            }
#pragma unroll
            for (int jd = 0; jd < 4; jd++) {
                const s16x8 v0 = *(const s16x8*)&Vs[cur][(jd * 16 + rr) * 64 + ((0 + quad) ^ swz8) * 8];
                const s16x8 v1 = *(const s16x8*)&Vs[cur][(jd * 16 + rr) * 64 + ((4 + quad) ^ swz8) * 8];
                __builtin_amdgcn_s_setprio(1);
#pragma unroll
                for (int g = 0; g < 2; g++) {
                    accO[g][jd] = MFMA16(v0, pB[g][0], accO[g][jd]);
                    accO[g][jd] = MFMA16(v1, pB[g][1], accO[g][jd]);
                }
                __builtin_amdgcn_s_setprio(0);
            }

            // single barrier per iter: drains the prefetch + releases cur buf
            __syncthreads();
            cur ^= 1;
        }
    };
    if (hasbias) kbloop(std::integral_constant<int, 1>{});
    else         kbloop(std::integral_constant<int, 0>{});

    // final l reduction across quads; epilogue via per-wave LDS transpose
    const int lr = lane >> 2, cch = lane & 3;
    const int pswl = (lr & 7) << 2;
#pragma unroll
    for (int g = 0; g < 2; g++) {
        float ls = lsum[g];
        ls += __shfl_xor(ls, 16);
        ls += __shfl_xor(ls, 32);
        float inv = 1.0f / ls;
#pragma unroll
        for (int jd = 0; jd < 4; jd++) {
            *(uint2*)&Ps[wave][rr * 32 + ((jd * 8 + quad * 2) ^ psw)] =
                make_uint2(pk2bf(accO[g][jd][0] * inv, accO[g][jd][1] * inv),
                           pk2bf(accO[g][jd][2] * inv, accO[g][jd][3] * inv));
        }
        uint4 w0 = *(const uint4*)&Ps[wave][lr * 32 + ((cch * 8) ^ pswl)];
        uint4 w1 = *(const uint4*)&Ps[wave][lr * 32 + ((cch * 8 + 4) ^ pswl)];
        size_t ob = ((size_t)(b * PL + q0 + g * 64 + wave * 16 + lr) * PC + h * PD);
        *(uint4*)(O + ob + cch * 16)     = w0;
        *(uint4*)(O + ob + cch * 16 + 8) = w1;
    }
}

// ---------------------------------------------------------------------------
// Kernel 4: out-proj GEMM, transposed compute Out^T-style (n in reg), BK=64.
// Out = Oh(8192x1024) . Wph(1024x1024)^T + bp, fp32 out, float4 stores.
// (no XCD swizzle — R11 regression)
// ---------------------------------------------------------------------------
__global__ __launch_bounds__(256) void gemm_proj_mfma(
    const unsigned short* __restrict__ Ah,
    const unsigned short* __restrict__ Wh,
    const float* __restrict__ bp, float* __restrict__ Out)
{
    __shared__ unsigned short As[128 * 64];
    __shared__ unsigned short Bs[128 * 64];
    const int tid  = threadIdx.x;
    const int wave = tid >> 6, lane = tid & 63;
    const int wm = wave & 1, wn = wave >> 1;
    const int quad = lane >> 4, rr = lane & 15;
    const int m0 = blockIdx.x * 128, n0 = blockIdx.y * 128;

    f32x4 acc[4][4];   // i over n sub-tiles, j over m sub-tiles
#pragma unroll
    for (int i = 0; i < 4; i++)
#pragma unroll
        for (int j = 0; j < 4; j++) acc[i][j] = (f32x4){0.f, 0.f, 0.f, 0.f};

    const int r8 = lane >> 3;
    const int c8 = lane & 7;
    const int g  = c8 ^ r8;
    const unsigned short* gA = Ah + (size_t)(m0 + wave * 32 + r8) * 1024 + g * 8;
    const unsigned short* gB = Wh + (size_t)(n0 + wave * 32 + r8) * 1024 + g * 8;
    unsigned short* lA = &As[(wave * 32) * 64];
    unsigned short* lB = &Bs[(wave * 32) * 64];

    const int swz8 = rr & 7;

    for (int k0 = 0; k0 < 16; k0++) {
#pragma unroll
        for (int t = 0; t < 4; t++) {
            gl2lds16(gA + (size_t)t * 8192, &lA[(t * 8) * 64]);
            gl2lds16(gB + (size_t)t * 8192, &lB[(t * 8) * 64]);
        }
        gA += 64; gB += 64;
        __syncthreads();

#pragma unroll
        for (int kk = 0; kk < 2; kk++) {
            const int coff = ((kk * 4 + quad) ^ swz8) * 8;
            s16x8 wf[4], xf[4];
#pragma unroll
            for (int i = 0; i < 4; i++)
                wf[i] = *(const s16x8*)&Bs[(wn * 64 + i * 16 + rr) * 64 + coff];
#pragma unroll
            for (int j = 0; j < 4; j++)
                xf[j] = *(const s16x8*)&As[(wm * 64 + j * 16 + rr) * 64 + coff];
#pragma unroll
            for (int i = 0; i < 4; i++)
#pragma unroll
                for (int j = 0; j < 4; j++)
                    acc[i][j] = MFMA16(wf[i], xf[j], acc[i][j]);
        }
        __syncthreads();
    }

    // epilogue: n = n0 + wn*64 + i*16 + quad*4 (+reg), m = m0 + wm*64 + j*16 + rr
#pragma unroll
    for (int i = 0; i < 4; i++) {
        const int nn = n0 + wn * 64 + i * 16 + quad * 4;
        const float4 bb = *(const float4*)(bp + nn);
#pragma unroll
        for (int j = 0; j < 4; j++) {
            const int m = m0 + wm * 64 + j * 16 + rr;
            float4 o = make_float4(acc[i][j][0] + bb.x, acc[i][j][1] + bb.y,
                                   acc[i][j][2] + bb.z, acc[i][j][3] + bb.w);
            *(float4*)(Out + (size_t)m * 1024 + nn) = o;
        }
    }
}

// ---------------------------------------------------------------------------
extern "C" void kernel_launch(void* const* d_in, const int* in_sizes, int n_in,
                              void* d_out, int out_size, void* d_ws, size_t ws_size,
                              hipStream_t stream)
{
    const float* x         = (const float*)d_in[0];
    const float* freqs     = (const float*)d_in[1];
    const float* attn_bias = (const float*)d_in[2];
    const float* W_qkv     = (const float*)d_in[3];
    const float* q_bias    = (const float*)d_in[4];
    const float* v_bias    = (const float*)d_in[5];
    const float* sml       = (const float*)d_in[6];
    const float* W_proj    = (const float*)d_in[7];
    const float* b_proj    = (const float*)d_in[8];
    float* out = (float*)d_out;

    unsigned char* w = (unsigned char*)d_ws;
    const size_t MB = 1ull << 20;
    unsigned short* xh  = (unsigned short*)(w + 0);        // 16 MiB
    unsigned short* wqh = (unsigned short*)(w + 16 * MB);  //  6 MiB
    unsigned short* wph = (unsigned short*)(w + 22 * MB);  //  2 MiB
    unsigned short* Qh  = (unsigned short*)(w + 24 * MB);  // 16 MiB (raw Q+bias)
    unsigned short* Kh  = (unsigned short*)(w + 40 * MB);  // 16 MiB (normed+roped)
    unsigned short* Vt  = (unsigned short*)(w + 72 * MB);  // 16 MiB (B,H,D,L), direct
    unsigned short* Oh  = (unsigned short*)(w + 88 * MB);  // 16 MiB (B,L,H,D)
    int*            flg = (int*)(w + 104 * MB);            //  4 B bias flag

    // 0. zero bias flag (ws is poisoned 0xAA)
    hipMemsetAsync(flg, 0, sizeof(int), stream);
    // 1. fused casts + bias scan
    cast3f_kernel<<<12544, 256, 0, stream>>>(x, W_qkv, W_proj, attn_bias,
                                             xh, wqh, wph, flg);
    // 2. QKV projection, all 3072 cols in ONE launch (vmode by blockIdx.y)
    gemm_qkv_lean<<<dim3(64, 24), 256, 0, stream>>>(
        xh, wqh, q_bias, v_bias, freqs, Qh, Kh, Vt);
    // 3. flash attention (staged dbuf, 4-wave, split bias/nobias loops)
    attn_mfma<<<dim3(128, 8), 256, 0, stream>>>(Qh, Kh, Vt, attn_bias, sml, flg, freqs, Oh);
    // 4. output projection (BK=64, transposed epilogue)
    gemm_proj_mfma<<<dim3(64, 8), 256, 0, stream>>>(Oh, wph, b_proj, out);
}